// Round 25
// baseline (1314.304 us; speedup 1.0000x reference)
//
#include <hip/hip_runtime.h>

#define NPTS 16384
#define CF 64
#define KCORR 2048
#define TQ 128
#define TC 128
#define NCH 8

typedef float v2f __attribute__((ext_vector_type(2)));

// Forced VOP3P packed FMA: two independent IEEE fp32 FMAs per instruction.
// Untied "=v" output (64-bit VReg_64) -- the tied-128-bit form is what
// broke round 15; untied 64-bit is supported, allocator coalesces d<-c.
__device__ __forceinline__ v2f pk_fma(v2f a, v2f b, v2f c) {
    v2f d;
    asm("v_pk_fma_f32 %0, %1, %2, %3" : "=v"(d) : "v"(a), "v"(b), "v"(c));
    return d;
}

// ---------------------------------------------------------------------------
// fp32 arithmetic variants (bit-exact emulation targets) -- DO NOT TOUCH.
// dot_avx2: the reference's weight arithmetic (8-lane FMA + halving tree).
// ---------------------------------------------------------------------------
__device__ __forceinline__ float dot_avx2(const float* __restrict__ a,
                                          const float* __restrict__ b) {
#pragma clang fp contract(off)
    float v0 = 0.f, v1 = 0.f, v2 = 0.f, v3 = 0.f;
    float v4 = 0.f, v5 = 0.f, v6 = 0.f, v7 = 0.f;
    #pragma unroll
    for (int i = 0; i < CF; i += 8) {
        v0 = fmaf(a[i + 0], b[i + 0], v0);
        v1 = fmaf(a[i + 1], b[i + 1], v1);
        v2 = fmaf(a[i + 2], b[i + 2], v2);
        v3 = fmaf(a[i + 3], b[i + 3], v3);
        v4 = fmaf(a[i + 4], b[i + 4], v4);
        v5 = fmaf(a[i + 5], b[i + 5], v5);
        v6 = fmaf(a[i + 6], b[i + 6], v6);
        v7 = fmaf(a[i + 7], b[i + 7], v7);
    }
    float u0 = v0 + v4, u1 = v1 + v5, u2 = v2 + v6, u3 = v3 + v7;
    float t0 = u0 + u2, t1 = u1 + u3;
    return t0 + t1;
}

// numpy pairwise_sum (selection-side row norms; same bits as round 12).
__device__ __forceinline__ float row_sumsq(const float* __restrict__ x) {
#pragma clang fp contract(off)
    float r[8];
    #pragma unroll
    for (int j = 0; j < 8; ++j) r[j] = x[j] * x[j];
    #pragma unroll
    for (int i = 8; i < 64; i += 8) {
        #pragma unroll
        for (int j = 0; j < 8; ++j) { float p = x[i + j] * x[i + j]; r[j] = r[j] + p; }
    }
    return ((r[0] + r[1]) + (r[2] + r[3])) + ((r[4] + r[5]) + (r[6] + r[7]));
}

// ---------------------------------------------------------------------------
// prep: per-row sum of squares. One thread per row. (unchanged)
// ---------------------------------------------------------------------------
__global__ __launch_bounds__(256) void prep_kernel(
    const float* __restrict__ src_feats, const float* __restrict__ tgt_feats,
    float* __restrict__ qq_src, float* __restrict__ qq_tgt)
{
    int t = blockIdx.x * 256 + threadIdx.x;      // 0 .. 2*NPTS-1
    if (t >= 2 * NPTS) return;
    const float* f = (t < NPTS) ? src_feats : tgt_feats;
    float*      qq = (t < NPTS) ? qq_src    : qq_tgt;
    int n = (t < NPTS) ? t : t - NPTS;
    float x[CF];
    #pragma unroll
    for (int c = 0; c < CF; c += 4) {
        float4 v = *(const float4*)(f + (size_t)n * CF + c);
        x[c] = v.x; x[c+1] = v.y; x[c+2] = v.z; x[c+3] = v.w;
    }
    qq[n] = row_sumsq(x);
}

// ---------------------------------------------------------------------------
// top2 v15: r24's structure + FORCED v_pk_fma_f32 inner loop.
// Candidate pairs natural in LDS (64-bit reads); query splatted once per
// (qi, k-step), reused across 4 pk_fma. Each pair lane computes the
// IDENTICAL sequential ascending-k IEEE FMA chain (bit-exact; r24's exact
// pairing passed with absmax 0.0). Epilogue unpacks to r22's order.
// ---------------------------------------------------------------------------
__global__ __launch_bounds__(256, 3) void top2_kernel(
    const float* __restrict__ src_feats, const float* __restrict__ tgt_feats,
    const float* __restrict__ qq_src, const float* __restrict__ qq_tgt,
    float* __restrict__ pd0, float* __restrict__ pd1,
    int* __restrict__ pi0, int* __restrict__ pi1)
{
    const int side = blockIdx.z;
    const int ch   = blockIdx.y;
    const int qb   = blockIdx.x;
    const int tid  = threadIdx.x;
    const int ty   = tid >> 4;        // 0..15 : query subgroup (8 q each)
    const int tx   = tid & 15;        // 0..15 : candidate subgroup (4+4 c)
    const int chsz = NPTS / NCH;

    const float* qf  = (side == 0) ? src_feats : tgt_feats;
    const float* sf  = (side == 0) ? tgt_feats : src_feats;
    const float* qqp = (side == 0) ? qq_src    : qq_tgt;
    const float* ssp = (side == 0) ? qq_tgt    : qq_src;

    __shared__ float Qs[CF][TQ];     // 32 KiB, [k][query] (merge scratch later)
    __shared__ float Cs[32][TC];     // 16 KiB, [k-half][cand]

    // ---- stage Q tile once, full K: lane owns row (2-way LDS writes) ----
    #pragma unroll
    for (int i = 0; i < 8; ++i) {
        int flat = i * 256 + tid;            // 0..2047
        int k4   = flat >> 7;                // 0..15
        int row  = flat & 127;               // 0..127
        float4 v = *(const float4*)(qf + (size_t)(qb * TQ + row) * CF + k4 * 4);
        Qs[k4*4+0][row] = v.x; Qs[k4*4+1][row] = v.y;
        Qs[k4*4+2][row] = v.z; Qs[k4*4+3][row] = v.w;
    }

    float qqv[8];
    #pragma unroll
    for (int i = 0; i < 8; ++i) qqv[i] = qqp[qb * TQ + ty * 8 + i];

    float rd0[8], rd1[8];
    int   ri0[8], ri1[8];
    #pragma unroll
    for (int i = 0; i < 8; ++i) {
        rd0[i] = 3.4e38f; rd1[i] = 3.4e38f;
        ri0[i] = 0x7fffffff; ri1[i] = 0x7fffffff;
    }

    const int base = ch * chsz;
    for (int tile = 0; tile < chsz / TC; ++tile) {
        v2f acc2[8][4];
        #pragma unroll
        for (int a = 0; a < 8; ++a)
            #pragma unroll
            for (int b = 0; b < 4; ++b) acc2[a][b] = (v2f){0.0f, 0.0f};

        #pragma unroll
        for (int kh = 0; kh < 2; ++kh) {
            __syncthreads();
            // ---- stage C half-tile: lane owns row (2-way LDS writes) ----
            #pragma unroll
            for (int i = 0; i < 4; ++i) {
                int flat = i * 256 + tid;    // 0..1023
                int k4h  = flat >> 7;        // 0..7
                int row  = flat & 127;       // 0..127
                float4 v = *(const float4*)(sf +
                    (size_t)(base + tile * TC + row) * CF + kh * 32 + k4h * 4);
                Cs[k4h*4+0][row] = v.x; Cs[k4h*4+1][row] = v.y;
                Cs[k4h*4+2][row] = v.z; Cs[k4h*4+3][row] = v.w;
            }
            __syncthreads();

            const int kb = kh * 32;
            #pragma unroll 4
            for (int k = 0; k < 32; ++k) {
                float4 a0 = *(const float4*)&Qs[kb + k][ty * 8];      // bcast
                float4 a1 = *(const float4*)&Qs[kb + k][ty * 8 + 4];  // bcast
                const v2f* c2a = (const v2f*)&Cs[k][tx * 4];          // contig
                const v2f* c2b = (const v2f*)&Cs[k][64 + tx * 4];     // contig
                v2f cp[4] = {c2a[0], c2a[1], c2b[0], c2b[1]};
                float qv[8] = {a0.x, a0.y, a0.z, a0.w, a1.x, a1.y, a1.z, a1.w};
                #pragma unroll
                for (int qi = 0; qi < 8; ++qi) {
                    v2f qd = (v2f){qv[qi], qv[qi]};   // splat, reused 4x
                    #pragma unroll
                    for (int cp4 = 0; cp4 < 4; ++cp4)
                        acc2[qi][cp4] = pk_fma(qd, cp[cp4], acc2[qi][cp4]);
                }
            }
        }

        float ssv[8];
        #pragma unroll
        for (int i = 0; i < 4; ++i) {
            ssv[i]     = ssp[base + tile * TC + tx * 4 + i];
            ssv[4 + i] = ssp[base + tile * TC + 64 + tx * 4 + i];
        }

        // ---- top-2 update: unpack pairs into ascending thread-local order
        //      (ci 0..3 = group0 idx tx*4+ci; ci 4..7 = 64+tx*4+ci-4) ----
        #pragma unroll
        for (int qi = 0; qi < 8; ++qi) {
            float av[8] = { acc2[qi][0].x, acc2[qi][0].y,
                            acc2[qi][1].x, acc2[qi][1].y,
                            acc2[qi][2].x, acc2[qi][2].y,
                            acc2[qi][3].x, acc2[qi][3].y };
            float qqn = qqv[qi];
            #pragma unroll
            for (int ci = 0; ci < 8; ++ci) {
                float d2;
                {
#pragma clang fp contract(off)
                    float twod = 2.0f * av[ci];        // exact
                    float t1v  = qqn - twod;           // one RNE round
                    d2 = t1v + ssv[ci];                // one RNE round
                }
                int m = base + tile * TC + ((ci < 4) ? (tx * 4 + ci)
                                                     : (64 + tx * 4 + ci - 4));
                if (d2 < rd1[qi]) {
                    if (d2 < rd0[qi]) { rd1[qi] = rd0[qi]; ri1[qi] = ri0[qi];
                                        rd0[qi] = d2;      ri0[qi] = m; }
                    else              { rd1[qi] = d2;      ri1[qi] = m; }
                }
            }
        }
    }

    // ---- merge the 16 tx-slices per query via LDS (lexicographic (d,i)) ----
    __syncthreads();
    float* scratch = &Qs[0][0];                 // 32 KiB reuse: [16][128] x4
    float* md0 = scratch;
    float* md1 = scratch + 2048;
    int*   mi0 = (int*)(scratch + 4096);
    int*   mi1 = (int*)(scratch + 6144);
    #pragma unroll
    for (int qi = 0; qi < 8; ++qi) {
        int q = ty * 8 + qi;
        md0[tx * 128 + q] = rd0[qi]; md1[tx * 128 + q] = rd1[qi];
        mi0[tx * 128 + q] = ri0[qi]; mi1[tx * 128 + q] = ri1[qi];
    }
    __syncthreads();

    if (tid < TQ) {
        int q = tid;
        float d0 = 3.4e38f, d1 = 3.4e38f;
        int   i0 = 0x7fffffff, i1 = 0x7fffffff;
        for (int t = 0; t < 16; ++t) {
            float cd0 = md0[t * 128 + q], cd1 = md1[t * 128 + q];
            int   ci0 = mi0[t * 128 + q], ci1 = mi1[t * 128 + q];
            if (cd0 < d1 || (cd0 == d1 && ci0 < i1)) {
                if (cd0 < d0 || (cd0 == d0 && ci0 < i0)) {
                    d1 = d0; i1 = i0; d0 = cd0; i0 = ci0;
                } else { d1 = cd0; i1 = ci0; }
            }
            if (cd1 < d1 || (cd1 == d1 && ci1 < i1)) {
                if (cd1 < d0 || (cd1 == d0 && ci1 < i0)) {
                    d1 = d0; i1 = i0; d0 = cd1; i0 = ci1;
                } else { d1 = cd1; i1 = ci1; }
            }
        }
        size_t slot = ((size_t)side * NCH + ch) * NPTS + qb * TQ + q;
        pd0[slot] = d0; pd1[slot] = d1;
        pi0[slot] = i0; pi1[slot] = i1;
    }
}

// ---------------------------------------------------------------------------
// merge: NCH chunk partials (ascending chunk order, strict '<' keeps lowest
// index) -> sims via dot_avx2, weight in strict fp32. (r12-verified logic)
// ---------------------------------------------------------------------------
__global__ __launch_bounds__(256) void merge_kernel(
    const float* __restrict__ src_feats, const float* __restrict__ tgt_feats,
    const float* __restrict__ pd0, const float* __restrict__ pd1,
    const int* __restrict__ pi0, const int* __restrict__ pi1,
    float* __restrict__ wgt, int* __restrict__ bidx)
{
    int t = blockIdx.x * blockDim.x + threadIdx.x;   // 0 .. 2*NPTS-1
    if (t >= 2 * NPTS) return;
    int side = t >> 14, n = t & (NPTS - 1);

    float d0 = 3.4e38f, d1 = 3.4e38f;
    int i0 = 0, i1 = 0;
    for (int ch = 0; ch < NCH; ++ch) {
        size_t slot = ((size_t)side * NCH + ch) * NPTS + n;
        float cd0 = pd0[slot], cd1 = pd1[slot];
        int   ci0 = pi0[slot], ci1 = pi1[slot];
        if (cd0 < d1) {
            if (cd0 < d0) { d1 = d0; i1 = i0; d0 = cd0; i0 = ci0; }
            else          { d1 = cd0; i1 = ci0; }
        }
        if (cd1 < d1) {
            if (cd1 < d0) { d1 = d0; i1 = i0; d0 = cd1; i0 = ci1; }
            else          { d1 = cd1; i1 = ci1; }
        }
    }
    if (i0 < 0 || i0 >= NPTS) i0 = 0;
    if (i1 < 0 || i1 >= NPTS) i1 = 0;

    const float* qf = (side == 0) ? src_feats : tgt_feats;
    const float* sf = (side == 0) ? tgt_feats : src_feats;

    float q[CF];
    #pragma unroll
    for (int c = 0; c < CF; c += 4) {
        float4 v = *(const float4*)(qf + (size_t)n * CF + c);
        q[c] = v.x; q[c+1] = v.y; q[c+2] = v.z; q[c+3] = v.w;
    }

    float dotA = dot_avx2(sf + (size_t)i0 * CF, q);
    float dotB = dot_avx2(sf + (size_t)i1 * CF, q);

    float w;
    {
#pragma clang fp contract(off)
        float sim0 = 1.0f - dotA;
        float sim1 = 1.0f - dotB;
        float den  = sim1 + 1e-8f;
        w = 1.0f - sim0 / den;
    }
    wgt[t]  = w;
    bidx[t] = i0;
}

// ---------------------------------------------------------------------------
// rank + gather (unchanged from the passing round)
// ---------------------------------------------------------------------------
__global__ __launch_bounds__(256) void rank_gather_kernel(
    const float* __restrict__ wgt, const int* __restrict__ bidx,
    const float* __restrict__ src_points, const float* __restrict__ tgt_points,
    const float* __restrict__ src_feats,  const float* __restrict__ tgt_feats,
    float* __restrict__ out)
{
    const int side = blockIdx.y;
    const int n = blockIdx.x * 256 + threadIdx.x;     // 0 .. NPTS-1
    const float* w = wgt + (size_t)side * NPTS;
    const float wn = w[n];

    __shared__ float tile[4096];
    int cnt = 0;
    for (int t0 = 0; t0 < NPTS; t0 += 4096) {
        __syncthreads();
        for (int j = threadIdx.x; j < 4096; j += 256) tile[j] = w[t0 + j];
        __syncthreads();
        #pragma unroll 8
        for (int j = 0; j < 4096; ++j) {
            float wj = tile[j];
            int jj = t0 + j;
            cnt += (wj > wn) || (wj == wn && jj < n);
        }
    }

    if (cnt < KCORR) {
        int r = side * KCORR + cnt;
        int sidx = bidx[(size_t)side * NPTS + n];
        if (sidx < 0) sidx = 0;
        int src_row = (side == 0) ? n : sidx;
        int tgt_row = (side == 0) ? sidx : n;

        float* out_srcP = out;                          // [2K,3]
        float* out_tgtP = out + 2 * KCORR * 3;          // [2K,3]
        float* out_srcF = out + 4 * KCORR * 3;          // [2K,64]
        float* out_tgtF = out_srcF + 2 * KCORR * CF;    // [2K,64]
        float* out_w    = out_tgtF + 2 * KCORR * CF;    // [2K]

        #pragma unroll
        for (int k = 0; k < 3; ++k) {
            out_srcP[(size_t)r * 3 + k] = src_points[(size_t)src_row * 3 + k];
            out_tgtP[(size_t)r * 3 + k] = tgt_points[(size_t)tgt_row * 3 + k];
        }
        const float4* sfr = (const float4*)(src_feats + (size_t)src_row * CF);
        const float4* tfr = (const float4*)(tgt_feats + (size_t)tgt_row * CF);
        float4* so = (float4*)(out_srcF + (size_t)r * CF);
        float4* to = (float4*)(out_tgtF + (size_t)r * CF);
        #pragma unroll
        for (int c = 0; c < CF / 4; ++c) { so[c] = sfr[c]; to[c] = tfr[c]; }
        out_w[r] = wn;
    }
}

// ---------------------------------------------------------------------------
extern "C" void kernel_launch(void* const* d_in, const int* in_sizes, int n_in,
                              void* d_out, int out_size, void* d_ws, size_t ws_size,
                              hipStream_t stream)
{
    const float* src_points = (const float*)d_in[0];
    const float* tgt_points = (const float*)d_in[1];
    const float* src_feats  = (const float*)d_in[2];
    const float* tgt_feats  = (const float*)d_in[3];
    float* out = (float*)d_out;
    (void)in_sizes; (void)n_in; (void)out_size; (void)ws_size;

    char* ws = (char*)d_ws;
    size_t off = 0;
    auto alloc = [&](size_t bytes) -> void* {
        void* p = ws + off;
        off += (bytes + 255) & ~(size_t)255;
        return p;
    };
    size_t nslots = (size_t)2 * NCH * NPTS;
    float* qq_src = (float*)alloc(sizeof(float) * NPTS);
    float* qq_tgt = (float*)alloc(sizeof(float) * NPTS);
    float* wgt    = (float*)alloc(sizeof(float) * 2 * NPTS);
    int*   bidx   = (int*)alloc(sizeof(int) * 2 * NPTS);
    float* pd0    = (float*)alloc(sizeof(float) * nslots);
    float* pd1    = (float*)alloc(sizeof(float) * nslots);
    int*   pi0    = (int*)alloc(sizeof(int) * nslots);
    int*   pi1    = (int*)alloc(sizeof(int) * nslots);

    prep_kernel<<<(2 * NPTS + 255) / 256, 256, 0, stream>>>(
        src_feats, tgt_feats, qq_src, qq_tgt);

    top2_kernel<<<dim3(NPTS / TQ, NCH, 2), 256, 0, stream>>>(
        src_feats, tgt_feats, qq_src, qq_tgt, pd0, pd1, pi0, pi1);

    merge_kernel<<<(2 * NPTS + 255) / 256, 256, 0, stream>>>(
        src_feats, tgt_feats, pd0, pd1, pi0, pi1, wgt, bidx);

    rank_gather_kernel<<<dim3(NPTS / 256, 2), 256, 0, stream>>>(
        wgt, bidx, src_points, tgt_points, src_feats, tgt_feats, out);
}

// Round 26
// 1224.553 us; speedup vs baseline: 1.0733x; 1.0733x over previous
//
#include <hip/hip_runtime.h>

#define NPTS 16384
#define CF 64
#define KCORR 2048
#define TQ 128
#define TC 128
#define NCH 8

typedef float v2f __attribute__((ext_vector_type(2)));

// Tied-accumulator packed FMA with op_sel query broadcast (VOP3P).
// Both result lanes use the LO (or HI) half of `a`; b/c lanes are normal.
// acc is tied in-place (%0) -> no d<-c mov (r25's regression cause).
__device__ __forceinline__ v2f pk_fma_lo(v2f a, v2f b, v2f c) {
    asm("v_pk_fma_f32 %0, %1, %2, %0 op_sel:[0,0,0] op_sel_hi:[0,1,1]"
        : "+v"(c) : "v"(a), "v"(b));
    return c;
}
__device__ __forceinline__ v2f pk_fma_hi(v2f a, v2f b, v2f c) {
    asm("v_pk_fma_f32 %0, %1, %2, %0 op_sel:[1,0,0] op_sel_hi:[1,1,1]"
        : "+v"(c) : "v"(a), "v"(b));
    return c;
}

// ---------------------------------------------------------------------------
// fp32 arithmetic variants (bit-exact emulation targets) -- DO NOT TOUCH.
// dot_avx2: the reference's weight arithmetic (8-lane FMA + halving tree).
// ---------------------------------------------------------------------------
__device__ __forceinline__ float dot_avx2(const float* __restrict__ a,
                                          const float* __restrict__ b) {
#pragma clang fp contract(off)
    float v0 = 0.f, v1 = 0.f, v2 = 0.f, v3 = 0.f;
    float v4 = 0.f, v5 = 0.f, v6 = 0.f, v7 = 0.f;
    #pragma unroll
    for (int i = 0; i < CF; i += 8) {
        v0 = fmaf(a[i + 0], b[i + 0], v0);
        v1 = fmaf(a[i + 1], b[i + 1], v1);
        v2 = fmaf(a[i + 2], b[i + 2], v2);
        v3 = fmaf(a[i + 3], b[i + 3], v3);
        v4 = fmaf(a[i + 4], b[i + 4], v4);
        v5 = fmaf(a[i + 5], b[i + 5], v5);
        v6 = fmaf(a[i + 6], b[i + 6], v6);
        v7 = fmaf(a[i + 7], b[i + 7], v7);
    }
    float u0 = v0 + v4, u1 = v1 + v5, u2 = v2 + v6, u3 = v3 + v7;
    float t0 = u0 + u2, t1 = u1 + u3;
    return t0 + t1;
}

// numpy pairwise_sum (selection-side row norms; same bits as round 12).
__device__ __forceinline__ float row_sumsq(const float* __restrict__ x) {
#pragma clang fp contract(off)
    float r[8];
    #pragma unroll
    for (int j = 0; j < 8; ++j) r[j] = x[j] * x[j];
    #pragma unroll
    for (int i = 8; i < 64; i += 8) {
        #pragma unroll
        for (int j = 0; j < 8; ++j) { float p = x[i + j] * x[i + j]; r[j] = r[j] + p; }
    }
    return ((r[0] + r[1]) + (r[2] + r[3])) + ((r[4] + r[5]) + (r[6] + r[7]));
}

// ---------------------------------------------------------------------------
// prep: per-row sum of squares. One thread per row. (unchanged)
// ---------------------------------------------------------------------------
__global__ __launch_bounds__(256) void prep_kernel(
    const float* __restrict__ src_feats, const float* __restrict__ tgt_feats,
    float* __restrict__ qq_src, float* __restrict__ qq_tgt)
{
    int t = blockIdx.x * 256 + threadIdx.x;      // 0 .. 2*NPTS-1
    if (t >= 2 * NPTS) return;
    const float* f = (t < NPTS) ? src_feats : tgt_feats;
    float*      qq = (t < NPTS) ? qq_src    : qq_tgt;
    int n = (t < NPTS) ? t : t - NPTS;
    float x[CF];
    #pragma unroll
    for (int c = 0; c < CF; c += 4) {
        float4 v = *(const float4*)(f + (size_t)n * CF + c);
        x[c] = v.x; x[c+1] = v.y; x[c+2] = v.z; x[c+3] = v.w;
    }
    qq[n] = row_sumsq(x);
}

// ---------------------------------------------------------------------------
// top2 v16: tied pk_fma + op_sel broadcast. Per k-step: 4 LDS reads + 32
// v_pk_fma_f32, ZERO movs (r25 had +d<-c mov and +splat movs). Queries stay
// packed in pairs (qp[4]); even/odd query uses op_sel lo/hi broadcast.
// Each lane computes the IDENTICAL ascending-k IEEE fmaf chain (the exact
// pairing that passed r24/r25 with absmax 0.0). Epilogue unpack unchanged.
// ---------------------------------------------------------------------------
__global__ __launch_bounds__(256, 3) void top2_kernel(
    const float* __restrict__ src_feats, const float* __restrict__ tgt_feats,
    const float* __restrict__ qq_src, const float* __restrict__ qq_tgt,
    float* __restrict__ pd0, float* __restrict__ pd1,
    int* __restrict__ pi0, int* __restrict__ pi1)
{
    const int side = blockIdx.z;
    const int ch   = blockIdx.y;
    const int qb   = blockIdx.x;
    const int tid  = threadIdx.x;
    const int ty   = tid >> 4;        // 0..15 : query subgroup (8 q each)
    const int tx   = tid & 15;        // 0..15 : candidate subgroup (4+4 c)
    const int chsz = NPTS / NCH;

    const float* qf  = (side == 0) ? src_feats : tgt_feats;
    const float* sf  = (side == 0) ? tgt_feats : src_feats;
    const float* qqp = (side == 0) ? qq_src    : qq_tgt;
    const float* ssp = (side == 0) ? qq_tgt    : qq_src;

    __shared__ float Qs[CF][TQ];     // 32 KiB, [k][query] (merge scratch later)
    __shared__ float Cs[32][TC];     // 16 KiB, [k-half][cand]

    // ---- stage Q tile once, full K: lane owns row (2-way LDS writes) ----
    #pragma unroll
    for (int i = 0; i < 8; ++i) {
        int flat = i * 256 + tid;            // 0..2047
        int k4   = flat >> 7;                // 0..15
        int row  = flat & 127;               // 0..127
        float4 v = *(const float4*)(qf + (size_t)(qb * TQ + row) * CF + k4 * 4);
        Qs[k4*4+0][row] = v.x; Qs[k4*4+1][row] = v.y;
        Qs[k4*4+2][row] = v.z; Qs[k4*4+3][row] = v.w;
    }

    float qqv[8];
    #pragma unroll
    for (int i = 0; i < 8; ++i) qqv[i] = qqp[qb * TQ + ty * 8 + i];

    float rd0[8], rd1[8];
    int   ri0[8], ri1[8];
    #pragma unroll
    for (int i = 0; i < 8; ++i) {
        rd0[i] = 3.4e38f; rd1[i] = 3.4e38f;
        ri0[i] = 0x7fffffff; ri1[i] = 0x7fffffff;
    }

    const int base = ch * chsz;
    for (int tile = 0; tile < chsz / TC; ++tile) {
        v2f acc2[8][4];
        #pragma unroll
        for (int a = 0; a < 8; ++a)
            #pragma unroll
            for (int b = 0; b < 4; ++b) acc2[a][b] = (v2f){0.0f, 0.0f};

        #pragma unroll
        for (int kh = 0; kh < 2; ++kh) {
            __syncthreads();
            // ---- stage C half-tile: lane owns row (2-way LDS writes) ----
            #pragma unroll
            for (int i = 0; i < 4; ++i) {
                int flat = i * 256 + tid;    // 0..1023
                int k4h  = flat >> 7;        // 0..7
                int row  = flat & 127;       // 0..127
                float4 v = *(const float4*)(sf +
                    (size_t)(base + tile * TC + row) * CF + kh * 32 + k4h * 4);
                Cs[k4h*4+0][row] = v.x; Cs[k4h*4+1][row] = v.y;
                Cs[k4h*4+2][row] = v.z; Cs[k4h*4+3][row] = v.w;
            }
            __syncthreads();

            const int kb = kh * 32;
            #pragma unroll 4
            for (int k = 0; k < 32; ++k) {
                float4 a0 = *(const float4*)&Qs[kb + k][ty * 8];      // bcast
                float4 a1 = *(const float4*)&Qs[kb + k][ty * 8 + 4];  // bcast
                const v2f* c2a = (const v2f*)&Cs[k][tx * 4];          // contig
                const v2f* c2b = (const v2f*)&Cs[k][64 + tx * 4];     // contig
                v2f cp[4] = {c2a[0], c2a[1], c2b[0], c2b[1]};
                v2f qp[4] = { (v2f){a0.x, a0.y}, (v2f){a0.z, a0.w},
                              (v2f){a1.x, a1.y}, (v2f){a1.z, a1.w} };
                #pragma unroll
                for (int qp4 = 0; qp4 < 4; ++qp4) {
                    #pragma unroll
                    for (int cp4 = 0; cp4 < 4; ++cp4) {
                        acc2[2*qp4+0][cp4] =
                            pk_fma_lo(qp[qp4], cp[cp4], acc2[2*qp4+0][cp4]);
                        acc2[2*qp4+1][cp4] =
                            pk_fma_hi(qp[qp4], cp[cp4], acc2[2*qp4+1][cp4]);
                    }
                }
            }
        }

        float ssv[8];
        #pragma unroll
        for (int i = 0; i < 4; ++i) {
            ssv[i]     = ssp[base + tile * TC + tx * 4 + i];
            ssv[4 + i] = ssp[base + tile * TC + 64 + tx * 4 + i];
        }

        // ---- top-2 update: unpack pairs into ascending thread-local order
        //      (ci 0..3 = group0 idx tx*4+ci; ci 4..7 = 64+tx*4+ci-4) ----
        #pragma unroll
        for (int qi = 0; qi < 8; ++qi) {
            float av[8] = { acc2[qi][0].x, acc2[qi][0].y,
                            acc2[qi][1].x, acc2[qi][1].y,
                            acc2[qi][2].x, acc2[qi][2].y,
                            acc2[qi][3].x, acc2[qi][3].y };
            float qqn = qqv[qi];
            #pragma unroll
            for (int ci = 0; ci < 8; ++ci) {
                float d2;
                {
#pragma clang fp contract(off)
                    float twod = 2.0f * av[ci];        // exact
                    float t1v  = qqn - twod;           // one RNE round
                    d2 = t1v + ssv[ci];                // one RNE round
                }
                int m = base + tile * TC + ((ci < 4) ? (tx * 4 + ci)
                                                     : (64 + tx * 4 + ci - 4));
                if (d2 < rd1[qi]) {
                    if (d2 < rd0[qi]) { rd1[qi] = rd0[qi]; ri1[qi] = ri0[qi];
                                        rd0[qi] = d2;      ri0[qi] = m; }
                    else              { rd1[qi] = d2;      ri1[qi] = m; }
                }
            }
        }
    }

    // ---- merge the 16 tx-slices per query via LDS (lexicographic (d,i)) ----
    __syncthreads();
    float* scratch = &Qs[0][0];                 // 32 KiB reuse: [16][128] x4
    float* md0 = scratch;
    float* md1 = scratch + 2048;
    int*   mi0 = (int*)(scratch + 4096);
    int*   mi1 = (int*)(scratch + 6144);
    #pragma unroll
    for (int qi = 0; qi < 8; ++qi) {
        int q = ty * 8 + qi;
        md0[tx * 128 + q] = rd0[qi]; md1[tx * 128 + q] = rd1[qi];
        mi0[tx * 128 + q] = ri0[qi]; mi1[tx * 128 + q] = ri1[qi];
    }
    __syncthreads();

    if (tid < TQ) {
        int q = tid;
        float d0 = 3.4e38f, d1 = 3.4e38f;
        int   i0 = 0x7fffffff, i1 = 0x7fffffff;
        for (int t = 0; t < 16; ++t) {
            float cd0 = md0[t * 128 + q], cd1 = md1[t * 128 + q];
            int   ci0 = mi0[t * 128 + q], ci1 = mi1[t * 128 + q];
            if (cd0 < d1 || (cd0 == d1 && ci0 < i1)) {
                if (cd0 < d0 || (cd0 == d0 && ci0 < i0)) {
                    d1 = d0; i1 = i0; d0 = cd0; i0 = ci0;
                } else { d1 = cd0; i1 = ci0; }
            }
            if (cd1 < d1 || (cd1 == d1 && ci1 < i1)) {
                if (cd1 < d0 || (cd1 == d0 && ci1 < i0)) {
                    d1 = d0; i1 = i0; d0 = cd1; i0 = ci1;
                } else { d1 = cd1; i1 = ci1; }
            }
        }
        size_t slot = ((size_t)side * NCH + ch) * NPTS + qb * TQ + q;
        pd0[slot] = d0; pd1[slot] = d1;
        pi0[slot] = i0; pi1[slot] = i1;
    }
}

// ---------------------------------------------------------------------------
// merge: NCH chunk partials (ascending chunk order, strict '<' keeps lowest
// index) -> sims via dot_avx2, weight in strict fp32. (r12-verified logic)
// ---------------------------------------------------------------------------
__global__ __launch_bounds__(256) void merge_kernel(
    const float* __restrict__ src_feats, const float* __restrict__ tgt_feats,
    const float* __restrict__ pd0, const float* __restrict__ pd1,
    const int* __restrict__ pi0, const int* __restrict__ pi1,
    float* __restrict__ wgt, int* __restrict__ bidx)
{
    int t = blockIdx.x * blockDim.x + threadIdx.x;   // 0 .. 2*NPTS-1
    if (t >= 2 * NPTS) return;
    int side = t >> 14, n = t & (NPTS - 1);

    float d0 = 3.4e38f, d1 = 3.4e38f;
    int i0 = 0, i1 = 0;
    for (int ch = 0; ch < NCH; ++ch) {
        size_t slot = ((size_t)side * NCH + ch) * NPTS + n;
        float cd0 = pd0[slot], cd1 = pd1[slot];
        int   ci0 = pi0[slot], ci1 = pi1[slot];
        if (cd0 < d1) {
            if (cd0 < d0) { d1 = d0; i1 = i0; d0 = cd0; i0 = ci0; }
            else          { d1 = cd0; i1 = ci0; }
        }
        if (cd1 < d1) {
            if (cd1 < d0) { d1 = d0; i1 = i0; d0 = cd1; i0 = ci1; }
            else          { d1 = cd1; i1 = ci1; }
        }
    }
    if (i0 < 0 || i0 >= NPTS) i0 = 0;
    if (i1 < 0 || i1 >= NPTS) i1 = 0;

    const float* qf = (side == 0) ? src_feats : tgt_feats;
    const float* sf = (side == 0) ? tgt_feats : src_feats;

    float q[CF];
    #pragma unroll
    for (int c = 0; c < CF; c += 4) {
        float4 v = *(const float4*)(qf + (size_t)n * CF + c);
        q[c] = v.x; q[c+1] = v.y; q[c+2] = v.z; q[c+3] = v.w;
    }

    float dotA = dot_avx2(sf + (size_t)i0 * CF, q);
    float dotB = dot_avx2(sf + (size_t)i1 * CF, q);

    float w;
    {
#pragma clang fp contract(off)
        float sim0 = 1.0f - dotA;
        float sim1 = 1.0f - dotB;
        float den  = sim1 + 1e-8f;
        w = 1.0f - sim0 / den;
    }
    wgt[t]  = w;
    bidx[t] = i0;
}

// ---------------------------------------------------------------------------
// rank + gather (unchanged from the passing round)
// ---------------------------------------------------------------------------
__global__ __launch_bounds__(256) void rank_gather_kernel(
    const float* __restrict__ wgt, const int* __restrict__ bidx,
    const float* __restrict__ src_points, const float* __restrict__ tgt_points,
    const float* __restrict__ src_feats,  const float* __restrict__ tgt_feats,
    float* __restrict__ out)
{
    const int side = blockIdx.y;
    const int n = blockIdx.x * 256 + threadIdx.x;     // 0 .. NPTS-1
    const float* w = wgt + (size_t)side * NPTS;
    const float wn = w[n];

    __shared__ float tile[4096];
    int cnt = 0;
    for (int t0 = 0; t0 < NPTS; t0 += 4096) {
        __syncthreads();
        for (int j = threadIdx.x; j < 4096; j += 256) tile[j] = w[t0 + j];
        __syncthreads();
        #pragma unroll 8
        for (int j = 0; j < 4096; ++j) {
            float wj = tile[j];
            int jj = t0 + j;
            cnt += (wj > wn) || (wj == wn && jj < n);
        }
    }

    if (cnt < KCORR) {
        int r = side * KCORR + cnt;
        int sidx = bidx[(size_t)side * NPTS + n];
        if (sidx < 0) sidx = 0;
        int src_row = (side == 0) ? n : sidx;
        int tgt_row = (side == 0) ? sidx : n;

        float* out_srcP = out;                          // [2K,3]
        float* out_tgtP = out + 2 * KCORR * 3;          // [2K,3]
        float* out_srcF = out + 4 * KCORR * 3;          // [2K,64]
        float* out_tgtF = out_srcF + 2 * KCORR * CF;    // [2K,64]
        float* out_w    = out_tgtF + 2 * KCORR * CF;    // [2K]

        #pragma unroll
        for (int k = 0; k < 3; ++k) {
            out_srcP[(size_t)r * 3 + k] = src_points[(size_t)src_row * 3 + k];
            out_tgtP[(size_t)r * 3 + k] = tgt_points[(size_t)tgt_row * 3 + k];
        }
        const float4* sfr = (const float4*)(src_feats + (size_t)src_row * CF);
        const float4* tfr = (const float4*)(tgt_feats + (size_t)tgt_row * CF);
        float4* so = (float4*)(out_srcF + (size_t)r * CF);
        float4* to = (float4*)(out_tgtF + (size_t)r * CF);
        #pragma unroll
        for (int c = 0; c < CF / 4; ++c) { so[c] = sfr[c]; to[c] = tfr[c]; }
        out_w[r] = wn;
    }
}

// ---------------------------------------------------------------------------
extern "C" void kernel_launch(void* const* d_in, const int* in_sizes, int n_in,
                              void* d_out, int out_size, void* d_ws, size_t ws_size,
                              hipStream_t stream)
{
    const float* src_points = (const float*)d_in[0];
    const float* tgt_points = (const float*)d_in[1];
    const float* src_feats  = (const float*)d_in[2];
    const float* tgt_feats  = (const float*)d_in[3];
    float* out = (float*)d_out;
    (void)in_sizes; (void)n_in; (void)out_size; (void)ws_size;

    char* ws = (char*)d_ws;
    size_t off = 0;
    auto alloc = [&](size_t bytes) -> void* {
        void* p = ws + off;
        off += (bytes + 255) & ~(size_t)255;
        return p;
    };
    size_t nslots = (size_t)2 * NCH * NPTS;
    float* qq_src = (float*)alloc(sizeof(float) * NPTS);
    float* qq_tgt = (float*)alloc(sizeof(float) * NPTS);
    float* wgt    = (float*)alloc(sizeof(float) * 2 * NPTS);
    int*   bidx   = (int*)alloc(sizeof(int) * 2 * NPTS);
    float* pd0    = (float*)alloc(sizeof(float) * nslots);
    float* pd1    = (float*)alloc(sizeof(float) * nslots);
    int*   pi0    = (int*)alloc(sizeof(int) * nslots);
    int*   pi1    = (int*)alloc(sizeof(int) * nslots);

    prep_kernel<<<(2 * NPTS + 255) / 256, 256, 0, stream>>>(
        src_feats, tgt_feats, qq_src, qq_tgt);

    top2_kernel<<<dim3(NPTS / TQ, NCH, 2), 256, 0, stream>>>(
        src_feats, tgt_feats, qq_src, qq_tgt, pd0, pd1, pi0, pi1);

    merge_kernel<<<(2 * NPTS + 255) / 256, 256, 0, stream>>>(
        src_feats, tgt_feats, pd0, pd1, pi0, pi1, wgt, bidx);

    rank_gather_kernel<<<dim3(NPTS / 256, 2), 256, 0, stream>>>(
        wgt, bidx, src_points, tgt_points, src_feats, tgt_feats, out);
}